// Round 2
// baseline (582.311 us; speedup 1.0000x reference)
//
#include <hip/hip_runtime.h>
#include <hip/hip_bf16.h>

#define T_TOK 2048
#define H_DIM 1024
#define F_DIM 2816
#define E_NUM 8
#define K_TOP 2
#define NPAIR (T_TOK * K_TOP)

#define BM 128
#define BN 128
#define BK 32
#define KS 56              // LDS row stride in bf16 elems: 112B, 16B-aligned, 2-way banks (free)
#define MAXTILES 40        // sum ceil(n_e/BM) <= 4096/128 + 8 = 40

typedef __bf16 bf16_t;
typedef bf16_t bf16x8 __attribute__((ext_vector_type(8)));
typedef float f32x4 __attribute__((ext_vector_type(4)));

// meta layout in ws (ints):
// [0] nTiles ; [16..] tileE[48] ; [64..] tileRow[48] ; [112..] tileEnd[48] ; [160..] slot2pair[4096]
#define META_TILEE   16
#define META_TILEROW 64
#define META_TILEEND 112
#define META_S2P     160
#define ACT_OFFSET   65536   // byte offset of act buffer in ws

__global__ void moe_route(const int* __restrict__ ids, int* __restrict__ meta) {
    __shared__ int cnt[E_NUM], cur[E_NUM];
    const int tid = threadIdx.x;
    if (tid < E_NUM) cnt[tid] = 0;
    __syncthreads();
    for (int p = tid; p < NPAIR; p += blockDim.x)
        atomicAdd(&cnt[ids[p]], 1);
    __syncthreads();
    if (tid == 0) {
        int acc = 0, nt = 0;
        for (int e = 0; e < E_NUM; ++e) {
            cur[e] = acc;
            const int c = cnt[e];
            for (int r = 0; r < c; r += BM) {
                meta[META_TILEE + nt]   = e;
                meta[META_TILEROW + nt] = acc + r;
                meta[META_TILEEND + nt] = acc + c;
                ++nt;
            }
            acc += c;
        }
        meta[0] = nt;
    }
    __syncthreads();
    int* s2p = meta + META_S2P;
    for (int p = tid; p < NPAIR; p += blockDim.x) {
        const int e = ids[p];
        const int s = atomicAdd(&cur[e], 1);
        s2p[s] = p;
    }
}

__device__ inline bf16x8 zero8() {
    bf16x8 v;
#pragma unroll
    for (int j = 0; j < 8; ++j) v[j] = (bf16_t)0.0f;
    return v;
}

// GEMM1: act[slot][f] = silu(X@Wg^T) * (X@Wu^T), bf16 out. A=gathered tokens, B=gate_up rows (NT layout).
__global__ __launch_bounds__(256, 2) void moe_gemm1(
    const float* __restrict__ X, const float* __restrict__ Wgu,
    const int* __restrict__ meta, bf16_t* __restrict__ act)
{
    const int mt = blockIdx.x;
    if (mt >= meta[0]) return;
    const int nt   = blockIdx.y;
    const int e    = meta[META_TILEE + mt];
    const int row0 = meta[META_TILEROW + mt];
    const int rend = meta[META_TILEEND + mt];
    const int* s2p = meta + META_S2P;

    const float* Wg = Wgu + (size_t)e * (2 * F_DIM) * H_DIM + (size_t)nt * BN * H_DIM;
    const float* Wu = Wg + (size_t)F_DIM * H_DIM;

    __shared__ bf16_t As[BM][KS];
    __shared__ bf16_t Bgs[BN][KS];
    __shared__ bf16_t Bus[BN][KS];

    const int tid  = threadIdx.x;
    const int lane = tid & 63;
    const int wid  = tid >> 6;
    const int wm   = (wid >> 1) * 64;
    const int wn   = (wid & 1) * 64;
    const int fr   = lane & 15;
    const int fk   = (lane >> 4) * 8;

    // staging: 2 units/thread; unit u = tid + s*256: row = u>>2, koff = (u&3)*8
    const int koff = (tid & 3) * 8;
    const int rowu[2] = { tid >> 2, 64 + (tid >> 2) };
    const float* aptr[2]; const float* gptr[2]; const float* uptr[2];
    bool aval[2];
    bf16_t* awr[2]; bf16_t* gwr[2]; bf16_t* uwr[2];
#pragma unroll
    for (int s = 0; s < 2; ++s) {
        const int r = rowu[s];
        const int slot = row0 + r;
        aval[s] = (slot < rend);
        const int t = aval[s] ? (s2p[slot] >> 1) : 0;  // K_TOP==2: token = pair>>1
        aptr[s] = X + (size_t)t * H_DIM + koff;
        gptr[s] = Wg + (size_t)r * H_DIM + koff;
        uptr[s] = Wu + (size_t)r * H_DIM + koff;
        awr[s] = &As[r][koff];
        gwr[s] = &Bgs[r][koff];
        uwr[s] = &Bus[r][koff];
    }

    f32x4 accg[4][4];
    f32x4 accu[4][4];
    const f32x4 zf = {0.0f, 0.0f, 0.0f, 0.0f};
#pragma unroll
    for (int m = 0; m < 4; ++m)
#pragma unroll
        for (int n = 0; n < 4; ++n) { accg[m][n] = zf; accu[m][n] = zf; }

    for (int kk = 0; kk < H_DIM / BK; ++kk) {
        __syncthreads();
        const int go = kk * BK;
#pragma unroll
        for (int s = 0; s < 2; ++s) {
            f32x4 a0 = zf, a1 = zf;
            if (aval[s]) {
                a0 = *(const f32x4*)(aptr[s] + go);
                a1 = *(const f32x4*)(aptr[s] + go + 4);
            }
            const f32x4 g0 = *(const f32x4*)(gptr[s] + go);
            const f32x4 g1 = *(const f32x4*)(gptr[s] + go + 4);
            const f32x4 u0 = *(const f32x4*)(uptr[s] + go);
            const f32x4 u1 = *(const f32x4*)(uptr[s] + go + 4);
            bf16x8 av, gv, uv;
#pragma unroll
            for (int j = 0; j < 4; ++j) {
                av[j] = (bf16_t)a0[j]; av[j + 4] = (bf16_t)a1[j];
                gv[j] = (bf16_t)g0[j]; gv[j + 4] = (bf16_t)g1[j];
                uv[j] = (bf16_t)u0[j]; uv[j + 4] = (bf16_t)u1[j];
            }
            *(bf16x8*)awr[s] = av;
            *(bf16x8*)gwr[s] = gv;
            *(bf16x8*)uwr[s] = uv;
        }
        __syncthreads();

        bf16x8 af[4];
#pragma unroll
        for (int m = 0; m < 4; ++m)
            af[m] = *(const bf16x8*)&As[wm + m * 16 + fr][fk];
#pragma unroll
        for (int n = 0; n < 4; ++n) {
            const bf16x8 gf = *(const bf16x8*)&Bgs[wn + n * 16 + fr][fk];
            const bf16x8 uf = *(const bf16x8*)&Bus[wn + n * 16 + fr][fk];
#pragma unroll
            for (int m = 0; m < 4; ++m) {
                accg[m][n] = __builtin_amdgcn_mfma_f32_16x16x32_bf16(af[m], gf, accg[m][n], 0, 0, 0);
                accu[m][n] = __builtin_amdgcn_mfma_f32_16x16x32_bf16(af[m], uf, accu[m][n], 0, 0, 0);
            }
        }
    }

    // epilogue: act = silu(gate) * up -> bf16
    const int qrow = (lane >> 4) * 4;
#pragma unroll
    for (int m = 0; m < 4; ++m) {
#pragma unroll
        for (int q = 0; q < 4; ++q) {
            const int r = wm + m * 16 + qrow + q;
            const int slot = row0 + r;
            if (slot < rend) {
                bf16_t* arow = act + (size_t)slot * F_DIM + nt * BN + wn;
#pragma unroll
                for (int n = 0; n < 4; ++n) {
                    const float g = accg[m][n][q];
                    const float u = accu[m][n][q];
                    const float sg = 1.0f / (1.0f + __expf(-g));
                    arow[n * 16 + fr] = (bf16_t)(g * sg * u);
                }
            }
        }
    }
}

// GEMM2: out[t][h] += w * (act[slot] @ Wd[e]^T). A=act (bf16), B=down rows (NT layout).
__global__ __launch_bounds__(256, 2) void moe_gemm2(
    const bf16_t* __restrict__ act, const float* __restrict__ Wd,
    const float* __restrict__ tkw, const int* __restrict__ meta,
    float* __restrict__ out)
{
    const int mt = blockIdx.x;
    if (mt >= meta[0]) return;
    const int nt   = blockIdx.y;
    const int e    = meta[META_TILEE + mt];
    const int row0 = meta[META_TILEROW + mt];
    const int rend = meta[META_TILEEND + mt];
    const int* s2p = meta + META_S2P;

    const float* Wb = Wd + (size_t)e * H_DIM * F_DIM + (size_t)nt * BN * F_DIM;

    __shared__ bf16_t As[BM][KS];
    __shared__ bf16_t Bs[BN][KS];

    const int tid  = threadIdx.x;
    const int lane = tid & 63;
    const int wid  = tid >> 6;
    const int wm   = (wid >> 1) * 64;
    const int wn   = (wid & 1) * 64;
    const int fr   = lane & 15;
    const int fk   = (lane >> 4) * 8;

    const int koff = (tid & 3) * 8;
    const int rowu[2] = { tid >> 2, 64 + (tid >> 2) };
    const bf16_t* aptr[2]; const float* bptr[2];
    bool aval[2];
    bf16_t* awr[2]; bf16_t* bwr[2];
#pragma unroll
    for (int s = 0; s < 2; ++s) {
        const int r = rowu[s];
        const int slot = row0 + r;
        aval[s] = (slot < rend);
        aptr[s] = act + (size_t)(aval[s] ? slot : 0) * F_DIM + koff;
        bptr[s] = Wb + (size_t)r * F_DIM + koff;
        awr[s] = &As[r][koff];
        bwr[s] = &Bs[r][koff];
    }

    f32x4 acc[4][4];
    const f32x4 zf = {0.0f, 0.0f, 0.0f, 0.0f};
#pragma unroll
    for (int m = 0; m < 4; ++m)
#pragma unroll
        for (int n = 0; n < 4; ++n) acc[m][n] = zf;

    for (int kk = 0; kk < F_DIM / BK; ++kk) {
        __syncthreads();
        const int go = kk * BK;
#pragma unroll
        for (int s = 0; s < 2; ++s) {
            bf16x8 av = zero8();
            if (aval[s]) av = *(const bf16x8*)(aptr[s] + go);
            const f32x4 b0 = *(const f32x4*)(bptr[s] + go);
            const f32x4 b1 = *(const f32x4*)(bptr[s] + go + 4);
            bf16x8 bv;
#pragma unroll
            for (int j = 0; j < 4; ++j) {
                bv[j] = (bf16_t)b0[j]; bv[j + 4] = (bf16_t)b1[j];
            }
            *(bf16x8*)awr[s] = av;
            *(bf16x8*)bwr[s] = bv;
        }
        __syncthreads();

        bf16x8 af[4];
#pragma unroll
        for (int m = 0; m < 4; ++m)
            af[m] = *(const bf16x8*)&As[wm + m * 16 + fr][fk];
#pragma unroll
        for (int n = 0; n < 4; ++n) {
            const bf16x8 bf = *(const bf16x8*)&Bs[wn + n * 16 + fr][fk];
#pragma unroll
            for (int m = 0; m < 4; ++m)
                acc[m][n] = __builtin_amdgcn_mfma_f32_16x16x32_bf16(af[m], bf, acc[m][n], 0, 0, 0);
        }
    }

    // epilogue: scaled atomic scatter-add into out
    const int qrow = (lane >> 4) * 4;
#pragma unroll
    for (int m = 0; m < 4; ++m) {
#pragma unroll
        for (int q = 0; q < 4; ++q) {
            const int r = wm + m * 16 + qrow + q;
            const int slot = row0 + r;
            if (slot < rend) {
                const int p = s2p[slot];
                const int t = p >> 1;
                const float w = tkw[p];
                float* orow = out + (size_t)t * H_DIM + nt * BN + wn;
#pragma unroll
                for (int n = 0; n < 4; ++n)
                    atomicAdd(&orow[n * 16 + fr], w * acc[m][n][q]);
            }
        }
    }
}

extern "C" void kernel_launch(void* const* d_in, const int* in_sizes, int n_in,
                              void* d_out, int out_size, void* d_ws, size_t ws_size,
                              hipStream_t stream) {
    const float* X   = (const float*)d_in[0];
    const float* tkw = (const float*)d_in[1];
    const int*   ids = (const int*)d_in[2];
    const float* Wgu = (const float*)d_in[3];
    const float* Wd  = (const float*)d_in[4];
    float* out = (float*)d_out;

    int*    meta = (int*)d_ws;
    bf16_t* act  = (bf16_t*)((char*)d_ws + ACT_OFFSET);

    hipMemsetAsync(d_out, 0, (size_t)T_TOK * H_DIM * sizeof(float), stream);
    moe_route<<<1, 256, 0, stream>>>(ids, meta);
    moe_gemm1<<<dim3(MAXTILES, F_DIM / BN), 256, 0, stream>>>(X, Wgu, meta, act);
    moe_gemm2<<<dim3(MAXTILES, H_DIM / BN), 256, 0, stream>>>(act, Wd, tkw, meta, out);
}

// Round 4
// 506.131 us; speedup vs baseline: 1.1505x; 1.1505x over previous
//
#include <hip/hip_runtime.h>
#include <hip/hip_bf16.h>

#define T_TOK 2048
#define H_DIM 1024
#define F_DIM 2816
#define E_NUM 8
#define K_TOP 2
#define NPAIR (T_TOK * K_TOP)

#define BM 128
#define BN 128
#define BK 32
#define KS 56              // fallback path LDS stride
#define MAXTILES 40
#define NT1 22             // F/BN
#define NT2 8              // H/BN
#define KSPLIT2 2
#define FS2 (F_DIM / KSPLIT2)   // 1408
#define NK1 (H_DIM / BK)        // 32
#define NK2 (FS2 / BK)          // 44

typedef __bf16 bf16_t;
typedef bf16_t bf16x8 __attribute__((ext_vector_type(8)));
typedef float f32x4 __attribute__((ext_vector_type(4)));

// ws layout (bytes)
#define META_TILEE   16
#define META_TILEROW 64
#define META_TILEEND 112
#define META_S2P     160
#define ACT_OFFSET   65536ULL
#define XG_OFFSET    (ACT_OFFSET + 23068672ULL)   // act: 4096*2816*2
#define WGU_OFFSET   (XG_OFFSET + 8388608ULL)     // xg: 4096*1024*2
#define WD_OFFSET    (WGU_OFFSET + 92274688ULL)   // wgu_bf
#define WS_NEED      (WD_OFFSET + 46137344ULL)    // + wd_bf = 169,934,848

__device__ inline void gload_lds16(const void* g, void* l) {
    __builtin_amdgcn_global_load_lds(
        (const __attribute__((address_space(1))) void*)g,
        (__attribute__((address_space(3))) void*)l, 16, 0, 0);
}

__global__ void moe_route(const int* __restrict__ ids, int* __restrict__ meta) {
    __shared__ int cnt[E_NUM], cur[E_NUM];
    const int tid = threadIdx.x;
    if (tid < E_NUM) cnt[tid] = 0;
    __syncthreads();
    for (int p = tid; p < NPAIR; p += blockDim.x)
        atomicAdd(&cnt[ids[p]], 1);
    __syncthreads();
    if (tid == 0) {
        int acc = 0, nt = 0;
        for (int e = 0; e < E_NUM; ++e) {
            cur[e] = acc;
            const int c = cnt[e];
            for (int r = 0; r < c; r += BM) {
                meta[META_TILEE + nt]   = e;
                meta[META_TILEROW + nt] = acc + r;
                meta[META_TILEEND + nt] = acc + c;
                ++nt;
            }
            acc += c;
        }
        meta[0] = nt;
    }
    __syncthreads();
    int* s2p = meta + META_S2P;
    for (int p = tid; p < NPAIR; p += blockDim.x) {
        const int e = ids[p];
        const int s = atomicAdd(&cur[e], 1);
        s2p[s] = p;
    }
}

// ---- bf16 pre-convert path ----

__global__ void conv_bf(const float* __restrict__ src, bf16_t* __restrict__ dst, int n8) {
    for (int i = blockIdx.x * blockDim.x + threadIdx.x; i < n8; i += gridDim.x * blockDim.x) {
        const f32x4 a = *(const f32x4*)(src + (size_t)i * 8);
        const f32x4 b = *(const f32x4*)(src + (size_t)i * 8 + 4);
        bf16x8 v;
#pragma unroll
        for (int j = 0; j < 4; ++j) { v[j] = (bf16_t)a[j]; v[j + 4] = (bf16_t)b[j]; }
        *(bf16x8*)(dst + (size_t)i * 8) = v;
    }
}

__global__ void gather_x(const float* __restrict__ X, const int* __restrict__ meta,
                         bf16_t* __restrict__ xg) {
    const int slot = blockIdx.x;
    const int t = meta[META_S2P + slot] >> 1;   // K_TOP==2
    const float* src = X + (size_t)t * H_DIM + threadIdx.x * 8;
    bf16_t* dst = xg + (size_t)slot * H_DIM + threadIdx.x * 8;
    const f32x4 a = *(const f32x4*)src;
    const f32x4 b = *(const f32x4*)(src + 4);
    bf16x8 v;
#pragma unroll
    for (int j = 0; j < 4; ++j) { v[j] = (bf16_t)a[j]; v[j + 4] = (bf16_t)b[j]; }
    *(bf16x8*)dst = v;
}

// GEMM1 bf16: act[slot][f] = silu(Xg@Wg^T)*(Xg@Wu^T). global_load_lds staging, linear LDS.
__global__ __launch_bounds__(256, 2) void moe_gemm1_bf(
    const bf16_t* __restrict__ Xg, const bf16_t* __restrict__ Wgu,
    const int* __restrict__ meta, bf16_t* __restrict__ act)
{
    // 1-D swizzled grid: nwg=880, chunk 110/XCD; logical L = nt*40+mt (mt fastest)
    const int h = blockIdx.x;
    const int L = (h & 7) * (MAXTILES * NT1 / 8) + (h >> 3);
    const int mt = L % MAXTILES;
    const int nt = L / MAXTILES;
    if (mt >= meta[0]) return;
    const int e    = meta[META_TILEE + mt];
    const int row0 = meta[META_TILEROW + mt];
    const int rend = meta[META_TILEEND + mt];

    const bf16_t* Wg = Wgu + (size_t)e * (2 * F_DIM) * H_DIM + (size_t)nt * BN * H_DIM;
    const bf16_t* Wu = Wg + (size_t)F_DIM * H_DIM;

    __shared__ bf16_t As[BM][BK];
    __shared__ bf16_t Bgs[BN][BK];
    __shared__ bf16_t Bus[BN][BK];

    const int tid  = threadIdx.x;
    const int lane = tid & 63;
    const int w    = tid >> 6;
    const int wm   = (w >> 1) * 64;
    const int wn   = (w & 1) * 64;
    const int fr   = lane & 15;
    const int fk   = (lane >> 4) * 8;

    // staging: per call, wave covers 16 rows (lane>>2) x 4 col-chunks (lane&3)*8
    const int lr = lane >> 2;
    const int ce = (lane & 3) * 8;
    const bf16_t* a_src[2]; const bf16_t* g_src[2]; const bf16_t* u_src[2];
    bf16_t *a_dst[2], *g_dst[2], *u_dst[2];
#pragma unroll
    for (int i = 0; i < 2; ++i) {
        const int r = i * 64 + w * 16 + lr;
        a_src[i] = Xg + (size_t)(row0 + r) * H_DIM + ce;
        g_src[i] = Wg + (size_t)r * H_DIM + ce;
        u_src[i] = Wu + (size_t)r * H_DIM + ce;
        const int lb = (i * 4 + w) * 512;
        a_dst[i] = &As[0][0] + lb;
        g_dst[i] = &Bgs[0][0] + lb;
        u_dst[i] = &Bus[0][0] + lb;
    }

    f32x4 accg[4][4];
    f32x4 accu[4][4];
    const f32x4 zf = {0.0f, 0.0f, 0.0f, 0.0f};
#pragma unroll
    for (int m = 0; m < 4; ++m)
#pragma unroll
        for (int n = 0; n < 4; ++n) { accg[m][n] = zf; accu[m][n] = zf; }

    for (int kk = 0; kk < NK1; ++kk) {
        const int go = kk * BK;
#pragma unroll
        for (int i = 0; i < 2; ++i) {
            gload_lds16(a_src[i] + go, a_dst[i]);
            gload_lds16(g_src[i] + go, g_dst[i]);
            gload_lds16(u_src[i] + go, u_dst[i]);
        }
        __syncthreads();

        bf16x8 af[4];
#pragma unroll
        for (int m = 0; m < 4; ++m)
            af[m] = *(const bf16x8*)&As[wm + m * 16 + fr][fk];
#pragma unroll
        for (int n = 0; n < 4; ++n) {
            const bf16x8 gf = *(const bf16x8*)&Bgs[wn + n * 16 + fr][fk];
            const bf16x8 uf = *(const bf16x8*)&Bus[wn + n * 16 + fr][fk];
#pragma unroll
            for (int m = 0; m < 4; ++m) {
                accg[m][n] = __builtin_amdgcn_mfma_f32_16x16x32_bf16(af[m], gf, accg[m][n], 0, 0, 0);
                accu[m][n] = __builtin_amdgcn_mfma_f32_16x16x32_bf16(af[m], uf, accu[m][n], 0, 0, 0);
            }
        }
        __syncthreads();
    }

    const int qrow = (lane >> 4) * 4;
#pragma unroll
    for (int m = 0; m < 4; ++m) {
#pragma unroll
        for (int q = 0; q < 4; ++q) {
            const int r = wm + m * 16 + qrow + q;
            const int slot = row0 + r;
            if (slot < rend) {
                bf16_t* arow = act + (size_t)slot * F_DIM + nt * BN + wn;
#pragma unroll
                for (int n = 0; n < 4; ++n) {
                    const float g = accg[m][n][q];
                    const float u = accu[m][n][q];
                    const float sg = 1.0f / (1.0f + __expf(-g));
                    arow[n * 16 + fr] = (bf16_t)(g * sg * u);
                }
            }
        }
    }
}

// GEMM2 bf16: out[t][:] += w * act[slot] @ Wd[e]^T, K split in 2.
__global__ __launch_bounds__(256, 2) void moe_gemm2_bf(
    const bf16_t* __restrict__ act, const bf16_t* __restrict__ Wd,
    const float* __restrict__ tkw, const int* __restrict__ meta,
    float* __restrict__ out)
{
    // nwg = 40*8*2 = 640, chunk 80/XCD; L = ks*320 + nt*40 + mt
    const int h = blockIdx.x;
    const int L = (h & 7) * (MAXTILES * NT2 * KSPLIT2 / 8) + (h >> 3);
    const int mt = L % MAXTILES;
    const int q0 = L / MAXTILES;
    const int nt = q0 % NT2;
    const int ks = q0 / NT2;
    if (mt >= meta[0]) return;
    const int e    = meta[META_TILEE + mt];
    const int row0 = meta[META_TILEROW + mt];
    const int rend = meta[META_TILEEND + mt];
    const int* s2p = meta + META_S2P;

    const bf16_t* Wb = Wd + (size_t)e * H_DIM * F_DIM + (size_t)nt * BN * F_DIM + ks * FS2;
    const bf16_t* Ab = act + ks * FS2;

    __shared__ bf16_t As[BM][BK];
    __shared__ bf16_t Bs[BN][BK];

    const int tid  = threadIdx.x;
    const int lane = tid & 63;
    const int w    = tid >> 6;
    const int wm   = (w >> 1) * 64;
    const int wn   = (w & 1) * 64;
    const int fr   = lane & 15;
    const int fk   = (lane >> 4) * 8;

    const int lr = lane >> 2;
    const int ce = (lane & 3) * 8;
    const bf16_t* a_src[2]; const bf16_t* b_src[2];
    bf16_t *a_dst[2], *b_dst[2];
#pragma unroll
    for (int i = 0; i < 2; ++i) {
        const int r = i * 64 + w * 16 + lr;
        a_src[i] = Ab + (size_t)(row0 + r) * F_DIM + ce;
        b_src[i] = Wb + (size_t)r * F_DIM + ce;
        const int lb = (i * 4 + w) * 512;
        a_dst[i] = &As[0][0] + lb;
        b_dst[i] = &Bs[0][0] + lb;
    }

    f32x4 acc[4][4];
    const f32x4 zf = {0.0f, 0.0f, 0.0f, 0.0f};
#pragma unroll
    for (int m = 0; m < 4; ++m)
#pragma unroll
        for (int n = 0; n < 4; ++n) acc[m][n] = zf;

    for (int kk = 0; kk < NK2; ++kk) {
        const int go = kk * BK;
#pragma unroll
        for (int i = 0; i < 2; ++i) {
            gload_lds16(a_src[i] + go, a_dst[i]);
            gload_lds16(b_src[i] + go, b_dst[i]);
        }
        __syncthreads();

        bf16x8 af[4];
#pragma unroll
        for (int m = 0; m < 4; ++m)
            af[m] = *(const bf16x8*)&As[wm + m * 16 + fr][fk];
#pragma unroll
        for (int n = 0; n < 4; ++n) {
            const bf16x8 bf = *(const bf16x8*)&Bs[wn + n * 16 + fr][fk];
#pragma unroll
            for (int m = 0; m < 4; ++m)
                acc[m][n] = __builtin_amdgcn_mfma_f32_16x16x32_bf16(af[m], bf, acc[m][n], 0, 0, 0);
        }
        __syncthreads();
    }

    const int qrow = (lane >> 4) * 4;
#pragma unroll
    for (int m = 0; m < 4; ++m) {
#pragma unroll
        for (int q = 0; q < 4; ++q) {
            const int r = wm + m * 16 + qrow + q;
            const int slot = row0 + r;
            if (slot < rend) {
                const int p = s2p[slot];
                const int t = p >> 1;
                const float wgt = tkw[p];
                float* orow = out + (size_t)t * H_DIM + nt * BN + wn;
#pragma unroll
                for (int n = 0; n < 4; ++n)
                    atomicAdd(&orow[n * 16 + fr], wgt * acc[m][n][q]);
            }
        }
    }
}

// ---- fallback path (round-2, fp32 reg-staged) ----

__device__ inline bf16x8 zero8() {
    bf16x8 v;
#pragma unroll
    for (int j = 0; j < 8; ++j) v[j] = (bf16_t)0.0f;
    return v;
}

__global__ __launch_bounds__(256, 2) void moe_gemm1(
    const float* __restrict__ X, const float* __restrict__ Wgu,
    const int* __restrict__ meta, bf16_t* __restrict__ act)
{
    const int mt = blockIdx.x;
    if (mt >= meta[0]) return;
    const int nt   = blockIdx.y;
    const int e    = meta[META_TILEE + mt];
    const int row0 = meta[META_TILEROW + mt];
    const int rend = meta[META_TILEEND + mt];
    const int* s2p = meta + META_S2P;

    const float* Wg = Wgu + (size_t)e * (2 * F_DIM) * H_DIM + (size_t)nt * BN * H_DIM;
    const float* Wu = Wg + (size_t)F_DIM * H_DIM;

    __shared__ bf16_t As[BM][KS];
    __shared__ bf16_t Bgs[BN][KS];
    __shared__ bf16_t Bus[BN][KS];

    const int tid  = threadIdx.x;
    const int lane = tid & 63;
    const int wid  = tid >> 6;
    const int wm   = (wid >> 1) * 64;
    const int wn   = (wid & 1) * 64;
    const int fr   = lane & 15;
    const int fk   = (lane >> 4) * 8;

    const int koff = (tid & 3) * 8;
    const int rowu[2] = { tid >> 2, 64 + (tid >> 2) };
    const float* aptr[2]; const float* gptr[2]; const float* uptr[2];
    bool aval[2];
    bf16_t* awr[2]; bf16_t* gwr[2]; bf16_t* uwr[2];
#pragma unroll
    for (int s = 0; s < 2; ++s) {
        const int r = rowu[s];
        const int slot = row0 + r;
        aval[s] = (slot < rend);
        const int t = aval[s] ? (s2p[slot] >> 1) : 0;
        aptr[s] = X + (size_t)t * H_DIM + koff;
        gptr[s] = Wg + (size_t)r * H_DIM + koff;
        uptr[s] = Wu + (size_t)r * H_DIM + koff;
        awr[s] = &As[r][koff];
        gwr[s] = &Bgs[r][koff];
        uwr[s] = &Bus[r][koff];
    }

    f32x4 accg[4][4];
    f32x4 accu[4][4];
    const f32x4 zf = {0.0f, 0.0f, 0.0f, 0.0f};
#pragma unroll
    for (int m = 0; m < 4; ++m)
#pragma unroll
        for (int n = 0; n < 4; ++n) { accg[m][n] = zf; accu[m][n] = zf; }

    for (int kk = 0; kk < NK1; ++kk) {
        __syncthreads();
        const int go = kk * BK;
#pragma unroll
        for (int s = 0; s < 2; ++s) {
            f32x4 a0 = zf, a1 = zf;
            if (aval[s]) {
                a0 = *(const f32x4*)(aptr[s] + go);
                a1 = *(const f32x4*)(aptr[s] + go + 4);
            }
            const f32x4 g0 = *(const f32x4*)(gptr[s] + go);
            const f32x4 g1 = *(const f32x4*)(gptr[s] + go + 4);
            const f32x4 u0 = *(const f32x4*)(uptr[s] + go);
            const f32x4 u1 = *(const f32x4*)(uptr[s] + go + 4);
            bf16x8 av, gv, uv;
#pragma unroll
            for (int j = 0; j < 4; ++j) {
                av[j] = (bf16_t)a0[j]; av[j + 4] = (bf16_t)a1[j];
                gv[j] = (bf16_t)g0[j]; gv[j + 4] = (bf16_t)g1[j];
                uv[j] = (bf16_t)u0[j]; uv[j + 4] = (bf16_t)u1[j];
            }
            *(bf16x8*)awr[s] = av;
            *(bf16x8*)gwr[s] = gv;
            *(bf16x8*)uwr[s] = uv;
        }
        __syncthreads();

        bf16x8 af[4];
#pragma unroll
        for (int m = 0; m < 4; ++m)
            af[m] = *(const bf16x8*)&As[wm + m * 16 + fr][fk];
#pragma unroll
        for (int n = 0; n < 4; ++n) {
            const bf16x8 gf = *(const bf16x8*)&Bgs[wn + n * 16 + fr][fk];
            const bf16x8 uf = *(const bf16x8*)&Bus[wn + n * 16 + fr][fk];
#pragma unroll
            for (int m = 0; m < 4; ++m) {
                accg[m][n] = __builtin_amdgcn_mfma_f32_16x16x32_bf16(af[m], gf, accg[m][n], 0, 0, 0);
                accu[m][n] = __builtin_amdgcn_mfma_f32_16x16x32_bf16(af[m], uf, accu[m][n], 0, 0, 0);
            }
        }
    }

    const int qrow = (lane >> 4) * 4;
#pragma unroll
    for (int m = 0; m < 4; ++m) {
#pragma unroll
        for (int q = 0; q < 4; ++q) {
            const int r = wm + m * 16 + qrow + q;
            const int slot = row0 + r;
            if (slot < rend) {
                bf16_t* arow = act + (size_t)slot * F_DIM + nt * BN + wn;
#pragma unroll
                for (int n = 0; n < 4; ++n) {
                    const float g = accg[m][n][q];
                    const float u = accu[m][n][q];
                    const float sg = 1.0f / (1.0f + __expf(-g));
                    arow[n * 16 + fr] = (bf16_t)(g * sg * u);
                }
            }
        }
    }
}

__global__ __launch_bounds__(256, 2) void moe_gemm2(
    const bf16_t* __restrict__ act, const float* __restrict__ Wd,
    const float* __restrict__ tkw, const int* __restrict__ meta,
    float* __restrict__ out)
{
    const int mt = blockIdx.x;
    if (mt >= meta[0]) return;
    const int nt   = blockIdx.y;
    const int e    = meta[META_TILEE + mt];
    const int row0 = meta[META_TILEROW + mt];
    const int rend = meta[META_TILEEND + mt];
    const int* s2p = meta + META_S2P;

    const float* Wb = Wd + (size_t)e * H_DIM * F_DIM + (size_t)nt * BN * F_DIM;

    __shared__ bf16_t As[BM][KS];
    __shared__ bf16_t Bs[BN][KS];

    const int tid  = threadIdx.x;
    const int lane = tid & 63;
    const int wid  = tid >> 6;
    const int wm   = (wid >> 1) * 64;
    const int wn   = (wid & 1) * 64;
    const int fr   = lane & 15;
    const int fk   = (lane >> 4) * 8;

    const int koff = (tid & 3) * 8;
    const int rowu[2] = { tid >> 2, 64 + (tid >> 2) };
    const bf16_t* aptr[2]; const float* bptr[2];
    bool aval[2];
    bf16_t* awr[2]; bf16_t* bwr[2];
#pragma unroll
    for (int s = 0; s < 2; ++s) {
        const int r = rowu[s];
        const int slot = row0 + r;
        aval[s] = (slot < rend);
        aptr[s] = act + (size_t)(aval[s] ? slot : 0) * F_DIM + koff;
        bptr[s] = Wb + (size_t)r * F_DIM + koff;
        awr[s] = &As[r][koff];
        bwr[s] = &Bs[r][koff];
    }

    f32x4 acc[4][4];
    const f32x4 zf = {0.0f, 0.0f, 0.0f, 0.0f};
#pragma unroll
    for (int m = 0; m < 4; ++m)
#pragma unroll
        for (int n = 0; n < 4; ++n) acc[m][n] = zf;

    for (int kk = 0; kk < F_DIM / BK; ++kk) {
        __syncthreads();
        const int go = kk * BK;
#pragma unroll
        for (int s = 0; s < 2; ++s) {
            bf16x8 av = zero8();
            if (aval[s]) av = *(const bf16x8*)(aptr[s] + go);
            const f32x4 b0 = *(const f32x4*)(bptr[s] + go);
            const f32x4 b1 = *(const f32x4*)(bptr[s] + go + 4);
            bf16x8 bv;
#pragma unroll
            for (int j = 0; j < 4; ++j) {
                bv[j] = (bf16_t)b0[j]; bv[j + 4] = (bf16_t)b1[j];
            }
            *(bf16x8*)awr[s] = av;
            *(bf16x8*)bwr[s] = bv;
        }
        __syncthreads();

        bf16x8 af[4];
#pragma unroll
        for (int m = 0; m < 4; ++m)
            af[m] = *(const bf16x8*)&As[wm + m * 16 + fr][fk];
#pragma unroll
        for (int n = 0; n < 4; ++n) {
            const bf16x8 bf = *(const bf16x8*)&Bs[wn + n * 16 + fr][fk];
#pragma unroll
            for (int m = 0; m < 4; ++m)
                acc[m][n] = __builtin_amdgcn_mfma_f32_16x16x32_bf16(af[m], bf, acc[m][n], 0, 0, 0);
        }
    }

    const int qrow = (lane >> 4) * 4;
#pragma unroll
    for (int m = 0; m < 4; ++m) {
#pragma unroll
        for (int q = 0; q < 4; ++q) {
            const int r = wm + m * 16 + qrow + q;
            const int slot = row0 + r;
            if (slot < rend) {
                const int p = s2p[slot];
                const int t = p >> 1;
                const float wgt = tkw[p];
                float* orow = out + (size_t)t * H_DIM + nt * BN + wn;
#pragma unroll
                for (int n = 0; n < 4; ++n)
                    atomicAdd(&orow[n * 16 + fr], wgt * acc[m][n][q]);
            }
        }
    }
}

extern "C" void kernel_launch(void* const* d_in, const int* in_sizes, int n_in,
                              void* d_out, int out_size, void* d_ws, size_t ws_size,
                              hipStream_t stream) {
    const float* X   = (const float*)d_in[0];
    const float* tkw = (const float*)d_in[1];
    const int*   ids = (const int*)d_in[2];
    const float* Wgu = (const float*)d_in[3];
    const float* Wd  = (const float*)d_in[4];
    float* out = (float*)d_out;

    int*    meta   = (int*)d_ws;
    bf16_t* act    = (bf16_t*)((char*)d_ws + ACT_OFFSET);

    hipMemsetAsync(d_out, 0, (size_t)T_TOK * H_DIM * sizeof(float), stream);
    moe_route<<<1, 256, 0, stream>>>(ids, meta);

    if (ws_size >= WS_NEED) {
        bf16_t* xg     = (bf16_t*)((char*)d_ws + XG_OFFSET);
        bf16_t* wgu_bf = (bf16_t*)((char*)d_ws + WGU_OFFSET);
        bf16_t* wd_bf  = (bf16_t*)((char*)d_ws + WD_OFFSET);
        conv_bf<<<2048, 256, 0, stream>>>(Wgu, wgu_bf, 5767168);
        conv_bf<<<2048, 256, 0, stream>>>(Wd, wd_bf, 2883584);
        gather_x<<<NPAIR, 128, 0, stream>>>(X, meta, xg);
        moe_gemm1_bf<<<MAXTILES * NT1, 256, 0, stream>>>(xg, wgu_bf, meta, act);
        moe_gemm2_bf<<<MAXTILES * NT2 * KSPLIT2, 256, 0, stream>>>(act, wd_bf, tkw, meta, out);
    } else {
        moe_gemm1<<<dim3(MAXTILES, NT1), 256, 0, stream>>>(X, Wgu, meta, act);
        moe_gemm2<<<dim3(MAXTILES, NT2), 256, 0, stream>>>(act, Wd, tkw, meta, out);
    }
}